// Round 1
// 311.459 us; speedup vs baseline: 1.1850x; 1.1850x over previous
//
#include <hip/hip_runtime.h>
#include <hip/hip_bf16.h>

// FastAttention (Performer/FAVOR+) — bf16 MFMA.
// B=4 H=16 L=4096 D_QK=64 D_V=64 M=256
#define Lq    4096
#define NORM  0.3535533905932738f      // 64^-0.25 (applied to x only)
#define SC    0.0625f                  // 1/sqrt(256)
#define EPSV  1e-6f
#define EPSV16 1.6e-5f                 // EPSV/SC: k2 drops the Q-side SC (2^-4, exact rescale)

typedef short short8 __attribute__((ext_vector_type(8)));
typedef short short4v __attribute__((ext_vector_type(4)));
typedef float float4v __attribute__((ext_vector_type(4)));

#define MFMA16(a, b, c) __builtin_amdgcn_mfma_f32_16x16x32_bf16(a, b, c, 0, 0, 0)

__device__ __forceinline__ short f2bf(float f) {
  unsigned u = __builtin_bit_cast(unsigned, f);
  unsigned r = (u + 0x7FFFu + ((u >> 16) & 1u)) >> 16;
  return (short)r;
}

#define PITCH 80                       // k1 LDS pitch (shorts)
#define P2    268                      // lphi pitch: 536 B rows — measured conflict-free
#define PP    68                       // k2 lproj pitch: 136 B rows -> 2-way max
#define PB    260                      // k2 lbT  pitch: 520 B rows -> balanced banks

// ws layout: buf1 fp32 [64][256][80], buf1T bf16 [64][80][256], projb bf16 [256][64]
#define BUF1_FLOATS ((size_t)64 * 256 * 80)
#define BUF1T_OFF   (BUF1_FLOATS * 4)
#define PROJB_OFF   (BUF1T_OFF + (size_t)64 * 20480 * 2)

// ---------------- Kernel 0: proj fp32 -> bf16 ----------------
__global__ __launch_bounds__(256)
void k0_proj(const float* __restrict__ proj, short* __restrict__ projb) {
  int i = (blockIdx.x * 256 + threadIdx.x) * 4;
  float4 v = *reinterpret_cast<const float4*>(proj + i);
  short4v o; o[0] = f2bf(v.x); o[1] = f2bf(v.y); o[2] = f2bf(v.z); o[3] = f2bf(v.w);
  *reinterpret_cast<short4v*>(projb + i) = o;
}

// ---------------- Kernel 1: per (chunk, bh), 512 keys -> atomicAdd buf1 fp32 ----------------
__global__ __launch_bounds__(256, 2)
void k1_build(const float* __restrict__ ks, const float* __restrict__ vs,
              const float* __restrict__ mask, const short* __restrict__ projb,
              float* __restrict__ buf1) {
  __shared__ short lx[64 * PITCH];     // [key][dim]
  __shared__ short lvT[80 * PITCH];    // [e][key]
  __shared__ short lphiT[256 * PITCH]; // [feat][key] — wave-private 64-row bands
  __shared__ float lhnp[64 * 16];
  __shared__ float lhn[64];
  __shared__ float lmfAll[512];

  const int t    = threadIdx.x;
  const int w    = t >> 6;
  const int lane = t & 63;
  const int c    = lane & 15;
  const int quad = lane >> 4;
  const int chunk = blockIdx.x;
  const int bh    = blockIdx.y;
  const int bidx  = bh >> 4;           // H = 16

  for (int i = t; i < 512; i += 256)
    lmfAll[i] = mask[(size_t)bidx * Lq + chunk * 512 + i] * SC;

  short8 pf[4][2];
#pragma unroll
  for (int nt = 0; nt < 4; ++nt)
#pragma unroll
    for (int h = 0; h < 2; ++h)
      pf[nt][h] = *reinterpret_cast<const short8*>(
          &projb[(size_t)(w * 64 + nt * 16 + c) * 64 + h * 32 + quad * 8]);

#pragma unroll
  for (int i = 0; i < 4; ++i) {
    int idx = i * 256 + t;
    int row = 64 + (idx >> 6), col = idx & 63;
    lvT[row * PITCH + col] = (row == 64) ? (short)0x3F80 : (short)0;
  }

  float4v acc[4][5];
#pragma unroll
  for (int mt = 0; mt < 4; ++mt)
#pragma unroll
    for (int nt = 0; nt < 5; ++nt) acc[mt][nt] = (float4v){0.f, 0.f, 0.f, 0.f};

  const float4* ks4 = reinterpret_cast<const float4*>(ks);
  const float4* vs4 = reinterpret_cast<const float4*>(vs);
  const int key0 = (t >> 4);
  const int d4   = t & 15;

  float4 kx[4], vx[4];
#pragma unroll
  for (int i = 0; i < 4; ++i) {
    size_t base = ((size_t)bh * Lq + chunk * 512 + (i * 16 + key0)) * 16 + d4;
    kx[i] = ks4[base]; vx[i] = vs4[base];
  }

  for (int kt = 0; kt < 8; ++kt) {
    __syncthreads();

#pragma unroll
    for (int i = 0; i < 4; ++i) {
      int key = i * 16 + key0;
      float4 v = kx[i];
      v.x *= NORM; v.y *= NORM; v.z *= NORM; v.w *= NORM;
      lhnp[key * 16 + d4] = v.x * v.x + v.y * v.y + v.z * v.z + v.w * v.w;
      short4v o; o[0] = f2bf(v.x); o[1] = f2bf(v.y); o[2] = f2bf(v.z); o[3] = f2bf(v.w);
      *reinterpret_cast<short4v*>(&lx[key * PITCH + d4 * 4]) = o;
      float4 u = vx[i];
      lvT[(d4 * 4 + 0) * PITCH + key] = f2bf(u.x);
      lvT[(d4 * 4 + 1) * PITCH + key] = f2bf(u.y);
      lvT[(d4 * 4 + 2) * PITCH + key] = f2bf(u.z);
      lvT[(d4 * 4 + 3) * PITCH + key] = f2bf(u.w);
    }
    __syncthreads();

    if (kt + 1 < 8) {
#pragma unroll
      for (int i = 0; i < 4; ++i) {
        size_t base = ((size_t)bh * Lq + chunk * 512 + (kt + 1) * 64 + (i * 16 + key0)) * 16 + d4;
        kx[i] = ks4[base]; vx[i] = vs4[base];
      }
    }
    if (t < 64) {
      float s = 0.f;
#pragma unroll
      for (int j = 0; j < 16; ++j) s += lhnp[t * 16 + j];
      lhn[t] = 0.5f * s;
    }
    __syncthreads();

#pragma unroll
    for (int mt = 0; mt < 4; ++mt) {
      short8 a0 = *reinterpret_cast<short8*>(&lx[(mt * 16 + c) * PITCH + quad * 8]);
      short8 a1 = *reinterpret_cast<short8*>(&lx[(mt * 16 + c) * PITCH + 32 + quad * 8]);
      float4v hn4 = *reinterpret_cast<float4v*>(&lhn[mt * 16 + quad * 4]);
      float4v mf4 = *reinterpret_cast<float4v*>(&lmfAll[kt * 64 + mt * 16 + quad * 4]);
#pragma unroll
      for (int nt = 0; nt < 4; ++nt) {
        float4v p = (float4v){0.f, 0.f, 0.f, 0.f};
        p = MFMA16(a0, pf[nt][0], p);
        p = MFMA16(a1, pf[nt][1], p);
        short4v ph;
#pragma unroll
        for (int r = 0; r < 4; ++r)
          ph[r] = f2bf(__expf(p[r] - hn4[r]) * mf4[r]);
        *reinterpret_cast<short4v*>(
            &lphiT[(w * 64 + nt * 16 + c) * PITCH + mt * 16 + quad * 4]) = ph;
      }
    }

    short8 bv[5][2];
#pragma unroll
    for (int nt = 0; nt < 5; ++nt) {
      bv[nt][0] = *reinterpret_cast<short8*>(&lvT[(nt * 16 + c) * PITCH + quad * 8]);
      bv[nt][1] = *reinterpret_cast<short8*>(&lvT[(nt * 16 + c) * PITCH + 32 + quad * 8]);
    }
#pragma unroll
    for (int mt = 0; mt < 4; ++mt) {
      short8 a0 = *reinterpret_cast<short8*>(&lphiT[(w * 64 + mt * 16 + c) * PITCH + quad * 8]);
      short8 a1 = *reinterpret_cast<short8*>(&lphiT[(w * 64 + mt * 16 + c) * PITCH + 32 + quad * 8]);
#pragma unroll
      for (int nt = 0; nt < 5; ++nt) {
        acc[mt][nt] = MFMA16(a0, bv[nt][0], acc[mt][nt]);
        acc[mt][nt] = MFMA16(a1, bv[nt][1], acc[mt][nt]);
      }
    }
  }

  float* bp = buf1 + (size_t)bh * 256 * 80;
#pragma unroll
  for (int mt = 0; mt < 4; ++mt)
#pragma unroll
    for (int nt = 0; nt < 5; ++nt)
#pragma unroll
      for (int r = 0; r < 4; ++r) {
        int feat = w * 64 + mt * 16 + quad * 4 + r;
        int e    = nt * 16 + c;
        atomicAdd(bp + (size_t)feat * 80 + e, acc[mt][nt][r]);
      }
}

// ---------------- Kernel 1.5: transpose + cvt: buf1T[bh][e][feat] bf16 ----------------
__global__ __launch_bounds__(256, 8)
void k1_reduce(const float* __restrict__ buf1, short* __restrict__ buf1T) {
  const int bh = blockIdx.x;
  const int s  = blockIdx.y;
  const int t  = threadIdx.x;
#pragma unroll
  for (int j = 0; j < 10; ++j) {
    int idx = s * 2560 + j * 256 + t;
    int e = idx >> 8, feat = idx & 255;
    buf1T[(size_t)bh * 20480 + idx] = f2bf(buf1[(size_t)bh * 20480 + feat * 80 + e]);
  }
}

// ---------------- Kernel 2: bh-looped, block-staged B operands ----------------
// Grid (64 qchunks, 8 bh-groups). Block = 256 thr (4 waves), 64 q rows, loops 8 bh.
// LDS: lproj staged once/block; buf1T double-buffered, staged once/bh (T14 split:
// issue global loads early, ds_write after phi). 137 KB LDS -> 1 block/CU by design.
__global__ __launch_bounds__(256, 1)
void k2_ctx(const float* __restrict__ qs, const short* __restrict__ projb,
            const short* __restrict__ buf1T, float* __restrict__ out) {
  __shared__ short lproj[256 * PP];    // 34816 B  [feat][dim]
  __shared__ short lbT[2][64 * PB];    // 66560 B  [e 0..63][feat]
  __shared__ short ldenS[2][256];      //  1024 B  row e=64 (denominator)
  __shared__ short lphi[64 * P2];      // 34304 B  [q(local)][feat], wave-private bands
  __shared__ float lhnw[64];

  const int t    = threadIdx.x;
  const int w    = t >> 6;
  const int lane = t & 63;
  const int c    = lane & 15;
  const int quad = lane >> 4;
  const int q0   = blockIdx.x * 64;
  const int bhb  = blockIdx.y * 8;

  // ---- prologue: stage lproj (once per block) ----
#pragma unroll
  for (int i = 0; i < 8; ++i) {
    int idx = i * 256 + t;
    int row = idx >> 3, col = (idx & 7) * 8;
    *reinterpret_cast<short8*>(&lproj[row * PP + col]) =
        *reinterpret_cast<const short8*>(&projb[(size_t)row * 64 + col]);
  }
  // ---- prologue: stage lbT[0]/ldenS[0] for bh = bhb ----
  {
    const short* bT = buf1T + (size_t)bhb * 20480;
#pragma unroll
    for (int i = 0; i < 8; ++i) {
      int idx = i * 256 + t;
      int e = idx >> 5, f = (idx & 31) * 8;
      *reinterpret_cast<short8*>(&lbT[0][e * PB + f]) =
          *reinterpret_cast<const short8*>(&bT[e * 256 + f]);
    }
    if (t < 32)
      *reinterpret_cast<short8*>(&ldenS[0][t * 8]) =
          *reinterpret_cast<const short8*>(&bT[16384 + t * 8]);
  }
  // ---- prologue: q regs for bh = bhb ----
  const float* qrow0 = qs + ((size_t)bhb * Lq + q0 + w * 16 + c) * 64;
  float4 v0 = *reinterpret_cast<const float4*>(qrow0 + quad * 8);
  float4 v1 = *reinterpret_cast<const float4*>(qrow0 + quad * 8 + 4);
  float4 v2 = *reinterpret_cast<const float4*>(qrow0 + 32 + quad * 8);
  float4 v3 = *reinterpret_cast<const float4*>(qrow0 + 32 + quad * 8 + 4);
  __syncthreads();

  int cur = 0;
  for (int it = 0; it < 8; ++it) {
    const int bh = bhb + it;

    // A) issue next-bh staging loads early (hide HBM/L2 latency under phi)
    short8 nb[8]; short8 nden; float4 n0, n1, n2, n3;
    if (it < 7) {
      const short* bTn = buf1T + (size_t)(bh + 1) * 20480;
#pragma unroll
      for (int i = 0; i < 8; ++i) {
        int idx = i * 256 + t;
        int e = idx >> 5, f = (idx & 31) * 8;
        nb[i] = *reinterpret_cast<const short8*>(&bTn[e * 256 + f]);
      }
      if (t < 32) nden = *reinterpret_cast<const short8*>(&bTn[16384 + t * 8]);
      const float* qn = qs + ((size_t)(bh + 1) * Lq + q0 + w * 16 + c) * 64;
      n0 = *reinterpret_cast<const float4*>(qn + quad * 8);
      n1 = *reinterpret_cast<const float4*>(qn + quad * 8 + 4);
      n2 = *reinterpret_cast<const float4*>(qn + 32 + quad * 8);
      n3 = *reinterpret_cast<const float4*>(qn + 32 + quad * 8 + 4);
    }

    // B) scale + |x|^2/2 + A-frags
    v0.x *= NORM; v0.y *= NORM; v0.z *= NORM; v0.w *= NORM;
    v1.x *= NORM; v1.y *= NORM; v1.z *= NORM; v1.w *= NORM;
    v2.x *= NORM; v2.y *= NORM; v2.z *= NORM; v2.w *= NORM;
    v3.x *= NORM; v3.y *= NORM; v3.z *= NORM; v3.w *= NORM;

    float s = v0.x * v0.x + v0.y * v0.y + v0.z * v0.z + v0.w * v0.w
            + v1.x * v1.x + v1.y * v1.y + v1.z * v1.z + v1.w * v1.w
            + v2.x * v2.x + v2.y * v2.y + v2.z * v2.z + v2.w * v2.w
            + v3.x * v3.x + v3.y * v3.y + v3.z * v3.z + v3.w * v3.w;
    s += __shfl_xor(s, 16);
    s += __shfl_xor(s, 32);
    if (quad == 0) lhnw[w * 16 + c] = 0.5f * s;

    short8 qa0, qa1;
    qa0[0] = f2bf(v0.x); qa0[1] = f2bf(v0.y); qa0[2] = f2bf(v0.z); qa0[3] = f2bf(v0.w);
    qa0[4] = f2bf(v1.x); qa0[5] = f2bf(v1.y); qa0[6] = f2bf(v1.z); qa0[7] = f2bf(v1.w);
    qa1[0] = f2bf(v2.x); qa1[1] = f2bf(v2.y); qa1[2] = f2bf(v2.z); qa1[3] = f2bf(v2.w);
    qa1[4] = f2bf(v3.x); qa1[5] = f2bf(v3.y); qa1[6] = f2bf(v3.z); qa1[7] = f2bf(v3.w);

    float4v hn4 = *reinterpret_cast<float4v*>(&lhnw[w * 16 + quad * 4]);

    // C) phi: B-frags from LDS lproj; exp (SC dropped, exact); wave-private lphi
#pragma unroll
    for (int nt = 0; nt < 16; ++nt) {
      short8 b0 = *reinterpret_cast<short8*>(&lproj[(nt * 16 + c) * PP + quad * 8]);
      short8 b1 = *reinterpret_cast<short8*>(&lproj[(nt * 16 + c) * PP + 32 + quad * 8]);
      float4v p = (float4v){0.f, 0.f, 0.f, 0.f};
      p = MFMA16(qa0, b0, p);
      p = MFMA16(qa1, b1, p);
#pragma unroll
      for (int r = 0; r < 4; ++r)
        lphi[(w * 16 + quad * 4 + r) * P2 + nt * 16 + c] =
            f2bf(__expf(p[r] - hn4[r]));
    }

    // D) write next-bh stage into the other LDS buffer (write-late half of T14)
    if (it < 7) {
#pragma unroll
      for (int i = 0; i < 8; ++i) {
        int idx = i * 256 + t;
        int e = idx >> 5, f = (idx & 31) * 8;
        *reinterpret_cast<short8*>(&lbT[cur ^ 1][e * PB + f]) = nb[i];
      }
      if (t < 32) *reinterpret_cast<short8*>(&ldenS[cur ^ 1][t * 8]) = nden;
    }

    // E) ctx: A from own lphi band, B from LDS-staged buf1T
    float4v cacc[5];
#pragma unroll
    for (int nt = 0; nt < 5; ++nt) cacc[nt] = (float4v){0.f, 0.f, 0.f, 0.f};
#pragma unroll
    for (int k2i = 0; k2i < 8; ++k2i) {
      short8 a = *reinterpret_cast<short8*>(&lphi[(w * 16 + c) * P2 + k2i * 32 + quad * 8]);
#pragma unroll
      for (int nt = 0; nt < 4; ++nt) {
        short8 b = *reinterpret_cast<short8*>(
            &lbT[cur][(nt * 16 + c) * PB + k2i * 32 + quad * 8]);
        cacc[nt] = MFMA16(a, b, cacc[nt]);
      }
      // denominator column (e=64 lives at c==0 of nt=4; e=65..79 are exact zeros)
      short8 bd;
      if (c == 0) bd = *reinterpret_cast<short8*>(&ldenS[cur][k2i * 32 + quad * 8]);
      else        bd = (short8){0, 0, 0, 0, 0, 0, 0, 0};
      cacc[4] = MFMA16(a, bd, cacc[4]);
    }

    // F) epilogue: den broadcast, divide (EPS rescaled by 1/SC), store
    float rinv[4];
#pragma unroll
    for (int r = 0; r < 4; ++r) {
      float den = __shfl(cacc[4][r], (lane & 48));
      den = fmaxf(den, EPSV16);
      rinv[r] = 1.0f / den;
    }
#pragma unroll
    for (int nt = 0; nt < 4; ++nt)
#pragma unroll
      for (int r = 0; r < 4; ++r) {
        int q = q0 + w * 16 + quad * 4 + r;
        out[((size_t)bh * Lq + q) * 64 + nt * 16 + c] = cacc[nt][r] * rinv[r];
      }

    __syncthreads();   // all waves done reading lbT[cur] before it is overwritten
    cur ^= 1;
    if (it < 7) { v0 = n0; v1 = n1; v2 = n2; v3 = n3; }
  }
}

extern "C" void kernel_launch(void* const* d_in, const int* in_sizes, int n_in,
                              void* d_out, int out_size, void* d_ws, size_t ws_size,
                              hipStream_t stream) {
  const float* qs   = (const float*)d_in[0];
  const float* ks   = (const float*)d_in[1];
  const float* vs   = (const float*)d_in[2];
  const float* mask = (const float*)d_in[3];
  const float* proj = (const float*)d_in[4];
  float* out  = (float*)d_out;
  float* buf1 = (float*)d_ws;
  short* buf1T = (short*)((char*)d_ws + BUF1T_OFF);
  short* projb = (short*)((char*)d_ws + PROJB_OFF);

  (void)in_sizes; (void)n_in; (void)out_size; (void)ws_size;

  hipMemsetAsync(buf1, 0, BUF1_FLOATS * sizeof(float), stream);
  k0_proj<<<dim3(16), 256, 0, stream>>>(proj, projb);
  k1_build<<<dim3(8, 64), 256, 0, stream>>>(ks, vs, mask, projb, buf1);
  k1_reduce<<<dim3(64, 8), 256, 0, stream>>>(buf1, buf1T);
  k2_ctx<<<dim3(64, 8), 256, 0, stream>>>(qs, projb, buf1T, out);
}

// Round 2
// 287.126 us; speedup vs baseline: 1.2854x; 1.0847x over previous
//
#include <hip/hip_runtime.h>
#include <hip/hip_bf16.h>

// FastAttention (Performer/FAVOR+) — bf16 MFMA.
// B=4 H=16 L=4096 D_QK=64 D_V=64 M=256
#define Lq    4096
#define NORM  0.3535533905932738f      // 64^-0.25 (applied to x only)
#define SC    0.0625f                  // 1/sqrt(256)
#define EPSV  1e-6f
#define EPSV16 1.6e-5f                 // EPSV/SC: k2 drops the Q-side SC (2^-4, exact rescale)

typedef short short8 __attribute__((ext_vector_type(8)));
typedef short short4v __attribute__((ext_vector_type(4)));
typedef float float4v __attribute__((ext_vector_type(4)));

#define MFMA16(a, b, c) __builtin_amdgcn_mfma_f32_16x16x32_bf16(a, b, c, 0, 0, 0)

__device__ __forceinline__ short f2bf(float f) {
  unsigned u = __builtin_bit_cast(unsigned, f);
  unsigned r = (u + 0x7FFFu + ((u >> 16) & 1u)) >> 16;
  return (short)r;
}

#define PITCH 80                       // k1 LDS pitch (shorts)
#define P2    268                      // lphi pitch: 536 B rows — measured conflict-free
#define PP    68                       // k2 lproj pitch
#define PB    260                      // k2 lbT  pitch

// ws layout: buf1 fp32 [64][256][80], buf1T bf16 [64][80][256], projb bf16 [256][64]
#define BUF1_FLOATS ((size_t)64 * 256 * 80)
#define BUF1T_OFF   (BUF1_FLOATS * 4)
#define PROJB_OFF   (BUF1T_OFF + (size_t)64 * 20480 * 2)

// ---------------- Kernel 0: proj fp32 -> bf16 ----------------
__global__ __launch_bounds__(256)
void k0_proj(const float* __restrict__ proj, short* __restrict__ projb) {
  int i = (blockIdx.x * 256 + threadIdx.x) * 4;
  float4 v = *reinterpret_cast<const float4*>(proj + i);
  short4v o; o[0] = f2bf(v.x); o[1] = f2bf(v.y); o[2] = f2bf(v.z); o[3] = f2bf(v.w);
  *reinterpret_cast<short4v*>(projb + i) = o;
}

// ---------------- Kernel 1: per (chunk, bh), 512 keys -> atomicAdd buf1 fp32 ----------------
__global__ __launch_bounds__(256, 2)
void k1_build(const float* __restrict__ ks, const float* __restrict__ vs,
              const float* __restrict__ mask, const short* __restrict__ projb,
              float* __restrict__ buf1) {
  __shared__ short lx[64 * PITCH];     // [key][dim]
  __shared__ short lvT[80 * PITCH];    // [e][key]
  __shared__ short lphiT[256 * PITCH]; // [feat][key] — wave-private 64-row bands
  __shared__ float lhnp[64 * 16];
  __shared__ float lhn[64];
  __shared__ float lmfAll[512];

  const int t    = threadIdx.x;
  const int w    = t >> 6;
  const int lane = t & 63;
  const int c    = lane & 15;
  const int quad = lane >> 4;
  const int chunk = blockIdx.x;
  const int bh    = blockIdx.y;
  const int bidx  = bh >> 4;           // H = 16

  for (int i = t; i < 512; i += 256)
    lmfAll[i] = mask[(size_t)bidx * Lq + chunk * 512 + i] * SC;

  short8 pf[4][2];
#pragma unroll
  for (int nt = 0; nt < 4; ++nt)
#pragma unroll
    for (int h = 0; h < 2; ++h)
      pf[nt][h] = *reinterpret_cast<const short8*>(
          &projb[(size_t)(w * 64 + nt * 16 + c) * 64 + h * 32 + quad * 8]);

#pragma unroll
  for (int i = 0; i < 4; ++i) {
    int idx = i * 256 + t;
    int row = 64 + (idx >> 6), col = idx & 63;
    lvT[row * PITCH + col] = (row == 64) ? (short)0x3F80 : (short)0;
  }

  float4v acc[4][5];
#pragma unroll
  for (int mt = 0; mt < 4; ++mt)
#pragma unroll
    for (int nt = 0; nt < 5; ++nt) acc[mt][nt] = (float4v){0.f, 0.f, 0.f, 0.f};

  const float4* ks4 = reinterpret_cast<const float4*>(ks);
  const float4* vs4 = reinterpret_cast<const float4*>(vs);
  const int key0 = (t >> 4);
  const int d4   = t & 15;

  float4 kx[4], vx[4];
#pragma unroll
  for (int i = 0; i < 4; ++i) {
    size_t base = ((size_t)bh * Lq + chunk * 512 + (i * 16 + key0)) * 16 + d4;
    kx[i] = ks4[base]; vx[i] = vs4[base];
  }

  for (int kt = 0; kt < 8; ++kt) {
    __syncthreads();

#pragma unroll
    for (int i = 0; i < 4; ++i) {
      int key = i * 16 + key0;
      float4 v = kx[i];
      v.x *= NORM; v.y *= NORM; v.z *= NORM; v.w *= NORM;
      lhnp[key * 16 + d4] = v.x * v.x + v.y * v.y + v.z * v.z + v.w * v.w;
      short4v o; o[0] = f2bf(v.x); o[1] = f2bf(v.y); o[2] = f2bf(v.z); o[3] = f2bf(v.w);
      *reinterpret_cast<short4v*>(&lx[key * PITCH + d4 * 4]) = o;
      float4 u = vx[i];
      lvT[(d4 * 4 + 0) * PITCH + key] = f2bf(u.x);
      lvT[(d4 * 4 + 1) * PITCH + key] = f2bf(u.y);
      lvT[(d4 * 4 + 2) * PITCH + key] = f2bf(u.z);
      lvT[(d4 * 4 + 3) * PITCH + key] = f2bf(u.w);
    }
    __syncthreads();

    if (kt + 1 < 8) {
#pragma unroll
      for (int i = 0; i < 4; ++i) {
        size_t base = ((size_t)bh * Lq + chunk * 512 + (kt + 1) * 64 + (i * 16 + key0)) * 16 + d4;
        kx[i] = ks4[base]; vx[i] = vs4[base];
      }
    }
    if (t < 64) {
      float s = 0.f;
#pragma unroll
      for (int j = 0; j < 16; ++j) s += lhnp[t * 16 + j];
      lhn[t] = 0.5f * s;
    }
    __syncthreads();

#pragma unroll
    for (int mt = 0; mt < 4; ++mt) {
      short8 a0 = *reinterpret_cast<short8*>(&lx[(mt * 16 + c) * PITCH + quad * 8]);
      short8 a1 = *reinterpret_cast<short8*>(&lx[(mt * 16 + c) * PITCH + 32 + quad * 8]);
      float4v hn4 = *reinterpret_cast<float4v*>(&lhn[mt * 16 + quad * 4]);
      float4v mf4 = *reinterpret_cast<float4v*>(&lmfAll[kt * 64 + mt * 16 + quad * 4]);
#pragma unroll
      for (int nt = 0; nt < 4; ++nt) {
        float4v p = (float4v){0.f, 0.f, 0.f, 0.f};
        p = MFMA16(a0, pf[nt][0], p);
        p = MFMA16(a1, pf[nt][1], p);
        short4v ph;
#pragma unroll
        for (int r = 0; r < 4; ++r)
          ph[r] = f2bf(__expf(p[r] - hn4[r]) * mf4[r]);
        *reinterpret_cast<short4v*>(
            &lphiT[(w * 64 + nt * 16 + c) * PITCH + mt * 16 + quad * 4]) = ph;
      }
    }

    short8 bv[5][2];
#pragma unroll
    for (int nt = 0; nt < 5; ++nt) {
      bv[nt][0] = *reinterpret_cast<short8*>(&lvT[(nt * 16 + c) * PITCH + quad * 8]);
      bv[nt][1] = *reinterpret_cast<short8*>(&lvT[(nt * 16 + c) * PITCH + 32 + quad * 8]);
    }
#pragma unroll
    for (int mt = 0; mt < 4; ++mt) {
      short8 a0 = *reinterpret_cast<short8*>(&lphiT[(w * 64 + mt * 16 + c) * PITCH + quad * 8]);
      short8 a1 = *reinterpret_cast<short8*>(&lphiT[(w * 64 + mt * 16 + c) * PITCH + 32 + quad * 8]);
#pragma unroll
      for (int nt = 0; nt < 5; ++nt) {
        acc[mt][nt] = MFMA16(a0, bv[nt][0], acc[mt][nt]);
        acc[mt][nt] = MFMA16(a1, bv[nt][1], acc[mt][nt]);
      }
    }
  }

  float* bp = buf1 + (size_t)bh * 256 * 80;
#pragma unroll
  for (int mt = 0; mt < 4; ++mt)
#pragma unroll
    for (int nt = 0; nt < 5; ++nt)
#pragma unroll
      for (int r = 0; r < 4; ++r) {
        int feat = w * 64 + mt * 16 + quad * 4 + r;
        int e    = nt * 16 + c;
        atomicAdd(bp + (size_t)feat * 80 + e, acc[mt][nt][r]);
      }
}

// ---------------- Kernel 1.5: transpose + cvt: buf1T[bh][e][feat] bf16 ----------------
__global__ __launch_bounds__(256, 8)
void k1_reduce(const float* __restrict__ buf1, short* __restrict__ buf1T) {
  const int bh = blockIdx.x;
  const int s  = blockIdx.y;
  const int t  = threadIdx.x;
#pragma unroll
  for (int j = 0; j < 10; ++j) {
    int idx = s * 2560 + j * 256 + t;
    int e = idx >> 8, feat = idx & 255;
    buf1T[(size_t)bh * 20480 + idx] = f2bf(buf1[(size_t)bh * 20480 + feat * 80 + e]);
  }
}

// ---------------- Kernel 2: 8 waves/block (2/SIMD), bh-looped, block-staged B ----------------
// Grid (32 qchunks, 8 bh-groups). Block = 512 thr (8 waves), 128 q rows, loops 8 bh.
// Single lbT buffer + T14 reg-staged next tile: issue loads early; ds_write after the
// ctx barrier so the write hides under the NEXT iteration's phi phase.
// LDS 137.7 KB -> 1 block/CU, but 8 waves = 2 waves/SIMD (vs 1 in prev round).
__global__ __launch_bounds__(512, 1)
void k2_ctx(const float* __restrict__ qs, const short* __restrict__ projb,
            const short* __restrict__ buf1T, float* __restrict__ out) {
  __shared__ short lproj[256 * PP];    // 34816 B  [feat][dim]
  __shared__ short lbT[64 * PB];       // 33280 B  [e 0..63][feat]
  __shared__ short lden[256];          //   512 B  row e=64 (denominator)
  __shared__ short lphi[128 * P2];     // 68608 B  [q(local)][feat], wave-private bands
  __shared__ float lhnw[128];

  const int t    = threadIdx.x;
  const int w    = t >> 6;             // 0..7
  const int lane = t & 63;
  const int c    = lane & 15;
  const int quad = lane >> 4;
  const int q0   = blockIdx.x * 128;
  const int bhb  = blockIdx.y * 8;

  // ---- prologue: stage lproj (once per block) ----
#pragma unroll
  for (int i = 0; i < 4; ++i) {
    int idx = i * 512 + t;
    int row = idx >> 3, col = (idx & 7) * 8;
    *reinterpret_cast<short8*>(&lproj[row * PP + col]) =
        *reinterpret_cast<const short8*>(&projb[(size_t)row * 64 + col]);
  }
  // ---- prologue: stage lbT/lden for bh = bhb ----
  {
    const short* bT = buf1T + (size_t)bhb * 20480;
#pragma unroll
    for (int i = 0; i < 4; ++i) {
      int idx = i * 512 + t;
      int e = idx >> 5, f = (idx & 31) * 8;
      *reinterpret_cast<short8*>(&lbT[e * PB + f]) =
          *reinterpret_cast<const short8*>(&bT[e * 256 + f]);
    }
    if (t < 32)
      *reinterpret_cast<short8*>(&lden[t * 8]) =
          *reinterpret_cast<const short8*>(&bT[16384 + t * 8]);
  }
  // ---- prologue: q regs for bh = bhb ----
  const float* qrow0 = qs + ((size_t)bhb * Lq + q0 + w * 16 + c) * 64;
  float4 v0 = *reinterpret_cast<const float4*>(qrow0 + quad * 8);
  float4 v1 = *reinterpret_cast<const float4*>(qrow0 + quad * 8 + 4);
  float4 v2 = *reinterpret_cast<const float4*>(qrow0 + 32 + quad * 8);
  float4 v3 = *reinterpret_cast<const float4*>(qrow0 + 32 + quad * 8 + 4);
  __syncthreads();

  for (int it = 0; it < 8; ++it) {
    const int bh = bhb + it;

    // A) issue next-bh staging loads early (hide HBM/L2 latency under phi+ctx)
    short8 nb[4]; short8 nden; float4 n0, n1, n2, n3;
    if (it < 7) {
      const short* bTn = buf1T + (size_t)(bh + 1) * 20480;
#pragma unroll
      for (int i = 0; i < 4; ++i) {
        int idx = i * 512 + t;
        int e = idx >> 5, f = (idx & 31) * 8;
        nb[i] = *reinterpret_cast<const short8*>(&bTn[e * 256 + f]);
      }
      if (t < 32) nden = *reinterpret_cast<const short8*>(&bTn[16384 + t * 8]);
      const float* qn = qs + ((size_t)(bh + 1) * Lq + q0 + w * 16 + c) * 64;
      n0 = *reinterpret_cast<const float4*>(qn + quad * 8);
      n1 = *reinterpret_cast<const float4*>(qn + quad * 8 + 4);
      n2 = *reinterpret_cast<const float4*>(qn + 32 + quad * 8);
      n3 = *reinterpret_cast<const float4*>(qn + 32 + quad * 8 + 4);
    }

    // B) scale + |x|^2/2 + A-frags
    v0.x *= NORM; v0.y *= NORM; v0.z *= NORM; v0.w *= NORM;
    v1.x *= NORM; v1.y *= NORM; v1.z *= NORM; v1.w *= NORM;
    v2.x *= NORM; v2.y *= NORM; v2.z *= NORM; v2.w *= NORM;
    v3.x *= NORM; v3.y *= NORM; v3.z *= NORM; v3.w *= NORM;

    float s = v0.x * v0.x + v0.y * v0.y + v0.z * v0.z + v0.w * v0.w
            + v1.x * v1.x + v1.y * v1.y + v1.z * v1.z + v1.w * v1.w
            + v2.x * v2.x + v2.y * v2.y + v2.z * v2.z + v2.w * v2.w
            + v3.x * v3.x + v3.y * v3.y + v3.z * v3.z + v3.w * v3.w;
    s += __shfl_xor(s, 16);
    s += __shfl_xor(s, 32);
    if (quad == 0) lhnw[w * 16 + c] = 0.5f * s;

    short8 qa0, qa1;
    qa0[0] = f2bf(v0.x); qa0[1] = f2bf(v0.y); qa0[2] = f2bf(v0.z); qa0[3] = f2bf(v0.w);
    qa0[4] = f2bf(v1.x); qa0[5] = f2bf(v1.y); qa0[6] = f2bf(v1.z); qa0[7] = f2bf(v1.w);
    qa1[0] = f2bf(v2.x); qa1[1] = f2bf(v2.y); qa1[2] = f2bf(v2.z); qa1[3] = f2bf(v2.w);
    qa1[4] = f2bf(v3.x); qa1[5] = f2bf(v3.y); qa1[6] = f2bf(v3.z); qa1[7] = f2bf(v3.w);

    float4v hn4 = *reinterpret_cast<float4v*>(&lhnw[w * 16 + quad * 4]);

    // C) phi: B-frags from LDS lproj; exp (SC dropped, exact); wave-private lphi
#pragma unroll
    for (int nt = 0; nt < 16; ++nt) {
      short8 b0 = *reinterpret_cast<short8*>(&lproj[(nt * 16 + c) * PP + quad * 8]);
      short8 b1 = *reinterpret_cast<short8*>(&lproj[(nt * 16 + c) * PP + 32 + quad * 8]);
      float4v p = (float4v){0.f, 0.f, 0.f, 0.f};
      p = MFMA16(qa0, b0, p);
      p = MFMA16(qa1, b1, p);
#pragma unroll
      for (int r = 0; r < 4; ++r)
        lphi[(w * 16 + quad * 4 + r) * P2 + nt * 16 + c] =
            f2bf(__expf(p[r] - hn4[r]));
    }

    __syncthreads();   // D) prev iter's lbT writes visible; all waves aligned

    // E) ctx: A from own lphi band, B from LDS-staged buf1T
    float4v cacc[5];
#pragma unroll
    for (int nt = 0; nt < 5; ++nt) cacc[nt] = (float4v){0.f, 0.f, 0.f, 0.f};
#pragma unroll
    for (int k2i = 0; k2i < 8; ++k2i) {
      short8 a = *reinterpret_cast<short8*>(&lphi[(w * 16 + c) * P2 + k2i * 32 + quad * 8]);
#pragma unroll
      for (int nt = 0; nt < 4; ++nt) {
        short8 b = *reinterpret_cast<short8*>(
            &lbT[(nt * 16 + c) * PB + k2i * 32 + quad * 8]);
        cacc[nt] = MFMA16(a, b, cacc[nt]);
      }
      // denominator column (e=64 lives at c==0 of nt=4; e=65..79 are exact zeros)
      short8 bd;
      if (c == 0) bd = *reinterpret_cast<short8*>(&lden[k2i * 32 + quad * 8]);
      else        bd = (short8){0, 0, 0, 0, 0, 0, 0, 0};
      cacc[4] = MFMA16(a, bd, cacc[4]);
    }

    // F) epilogue: den broadcast, divide (EPS rescaled by 1/SC), store
    float rinv[4];
#pragma unroll
    for (int r = 0; r < 4; ++r) {
      float den = __shfl(cacc[4][r], (lane & 48));
      den = fmaxf(den, EPSV16);
      rinv[r] = 1.0f / den;
    }
#pragma unroll
    for (int nt = 0; nt < 4; ++nt)
#pragma unroll
      for (int r = 0; r < 4; ++r) {
        int q = q0 + w * 16 + quad * 4 + r;
        out[((size_t)bh * Lq + q) * 64 + nt * 16 + c] = cacc[nt][r] * rinv[r];
      }

    __syncthreads();   // G-pre) all waves done reading lbT before overwrite

    // G) write next-bh stage into lbT (hides under next iter's phi phase)
    if (it < 7) {
#pragma unroll
      for (int i = 0; i < 4; ++i) {
        int idx = i * 512 + t;
        int e = idx >> 5, f = (idx & 31) * 8;
        *reinterpret_cast<short8*>(&lbT[e * PB + f]) = nb[i];
      }
      if (t < 32) *reinterpret_cast<short8*>(&lden[t * 8]) = nden;
      v0 = n0; v1 = n1; v2 = n2; v3 = n3;
    }
  }
}

extern "C" void kernel_launch(void* const* d_in, const int* in_sizes, int n_in,
                              void* d_out, int out_size, void* d_ws, size_t ws_size,
                              hipStream_t stream) {
  const float* qs   = (const float*)d_in[0];
  const float* ks   = (const float*)d_in[1];
  const float* vs   = (const float*)d_in[2];
  const float* mask = (const float*)d_in[3];
  const float* proj = (const float*)d_in[4];
  float* out  = (float*)d_out;
  float* buf1 = (float*)d_ws;
  short* buf1T = (short*)((char*)d_ws + BUF1T_OFF);
  short* projb = (short*)((char*)d_ws + PROJB_OFF);

  (void)in_sizes; (void)n_in; (void)out_size; (void)ws_size;

  hipMemsetAsync(buf1, 0, BUF1_FLOATS * sizeof(float), stream);
  k0_proj<<<dim3(16), 256, 0, stream>>>(proj, projb);
  k1_build<<<dim3(8, 64), 256, 0, stream>>>(ks, vs, mask, projb, buf1);
  k1_reduce<<<dim3(64, 8), 256, 0, stream>>>(buf1, buf1T);
  k2_ctx<<<dim3(32, 8), 512, 0, stream>>>(qs, projb, buf1T, out);
}